// Round 1
// baseline (1334.867 us; speedup 1.0000x reference)
//
#include <hip/hip_runtime.h>

#define BB 256
#define SS 1024
#define FF 64
#define HH 64
#define G4 256

__device__ __forceinline__ float sigmoidf_(float x) {
    // 1/(1+e^-x); rcp is ~1ulp, exp via v_exp_f32 — plenty for 1.5e-2 threshold
    return __builtin_amdgcn_rcpf(1.0f + __expf(-x));
}
__device__ __forceinline__ float tanhf_(float x) {
    // 1 - 2/(e^{2x}+1); saturates correctly at +/-inf
    return 1.0f - 2.0f * __builtin_amdgcn_rcpf(__expf(2.0f * x) + 1.0f);
}

// One block per batch element. 256 threads = 4 waves; thread g owns gate-output g
// (wave 0: i-gates, wave 1: f, wave 2: c, wave 3: o). Weights held in VGPRs
// (64+64 floats/thread). h broadcast via v_readlane (VALU), x row via uniform
// scalar loads. One __syncthreads per step with double-buffered z in LDS.
__global__ __launch_bounds__(256, 1)
void lstm_fused(const float* __restrict__ x,
                const float* __restrict__ wk,
                const float* __restrict__ rk,
                const float* __restrict__ bias,
                const float* __restrict__ dw,
                const float* __restrict__ db,
                float* __restrict__ out) {
    const int b = blockIdx.x;
    const int g = threadIdx.x;
    const int lane = g & 63;
    const int wave = g >> 6;

    // Per-thread weight columns (registers).
    float wx[FF];
    float wh[HH];
#pragma unroll
    for (int k = 0; k < FF; ++k) wx[k] = wk[k * G4 + g];
#pragma unroll
    for (int k = 0; k < HH; ++k) wh[k] = rk[k * G4 + g];
    const float bg  = bias[g];
    const float dwl = dw[lane];
    const float db0 = db[0];

    __shared__ float zbuf[2][G4];

    float h = 0.0f, c = 0.0f;
    const float* __restrict__ xb   = x + (size_t)b * SS * FF;
    float* __restrict__       outb = out + (size_t)b * SS;

    for (int t = 0; t < SS; ++t) {
        const float* __restrict__ xr = xb + t * FF;

        // Stage x row (wave-uniform addresses -> scalar loads, scheduled early)
        float xs[FF];
#pragma unroll
        for (int k = 0; k < FF; ++k) xs[k] = xr[k];

        float a0 = bg, a1 = 0.0f, a2 = 0.0f, a3 = 0.0f;

        // h-contribution: broadcast h[k] with v_readlane (each wave holds a
        // redundant copy of h distributed one element per lane).
        const int hb = __float_as_int(h);
#pragma unroll
        for (int k = 0; k < HH; k += 4) {
            a0 += __int_as_float(__builtin_amdgcn_readlane(hb, k + 0)) * wh[k + 0];
            a1 += __int_as_float(__builtin_amdgcn_readlane(hb, k + 1)) * wh[k + 1];
            a2 += __int_as_float(__builtin_amdgcn_readlane(hb, k + 2)) * wh[k + 2];
            a3 += __int_as_float(__builtin_amdgcn_readlane(hb, k + 3)) * wh[k + 3];
        }
        // x-contribution (scalar operand FMAs)
#pragma unroll
        for (int k = 0; k < FF; k += 4) {
            a0 += xs[k + 0] * wx[k + 0];
            a1 += xs[k + 1] * wx[k + 1];
            a2 += xs[k + 2] * wx[k + 2];
            a3 += xs[k + 3] * wx[k + 3];
        }
        const float z = (a0 + a1) + (a2 + a3);

        // Exchange z across waves (double buffer -> single barrier per step)
        zbuf[t & 1][g] = z;
        __syncthreads();
        const float zi = zbuf[t & 1][lane];
        const float zf = zbuf[t & 1][64 + lane];
        const float zc = zbuf[t & 1][128 + lane];
        const float zo = zbuf[t & 1][192 + lane];

        const float ig = sigmoidf_(zi);
        const float fg = sigmoidf_(zf);
        const float og = sigmoidf_(zo);
        c = fg * c + ig * tanhf_(zc);
        h = og * tanhf_(c);

        // Fused dense+sigmoid output: wave 0 reduces h . dense_w
        if (wave == 0) {
            float r = h * dwl;
#pragma unroll
            for (int m = 32; m >= 1; m >>= 1) r += __shfl_xor(r, m, 64);
            if (lane == 0) outb[t] = sigmoidf_(r + db0);
        }
    }
}

extern "C" void kernel_launch(void* const* d_in, const int* in_sizes, int n_in,
                              void* d_out, int out_size, void* d_ws, size_t ws_size,
                              hipStream_t stream) {
    const float* x    = (const float*)d_in[0];
    const float* wk   = (const float*)d_in[1];
    const float* rk   = (const float*)d_in[2];
    const float* bias = (const float*)d_in[3];
    const float* dw   = (const float*)d_in[4];
    const float* db   = (const float*)d_in[5];
    float* out = (float*)d_out;

    hipLaunchKernelGGL(lstm_fused, dim3(BB), dim3(256), 0, stream,
                       x, wk, rk, bias, dw, db, out);
}

// Round 2
// 1103.946 us; speedup vs baseline: 1.2092x; 1.2092x over previous
//
#include <hip/hip_runtime.h>

#define SS 1024
#define FF 64
#define HH 64
#define NG 256   // 4H gate columns
#define NT 512   // threads per block (8 waves = 2 per SIMD)
#define KH 32    // K-slice per thread (half of F/H)

__device__ __forceinline__ float sigmoidf_(float x) {
    return __builtin_amdgcn_rcpf(1.0f + __expf(-x));
}
__device__ __forceinline__ float tanhf_(float x) {
    // 1 - 2/(e^{2x}+1); saturates correctly at +/-inf
    return 1.0f - 2.0f * __builtin_amdgcn_rcpf(__expf(2.0f * x) + 1.0f);
}

// One block per batch element (256 blocks = 1 per CU).
// Thread (g = tid&255, half = tid>>8) computes the k in [half*32,(half+1)*32)
// partial of gate column g. Weights pinned in VGPRs via asm (compiler may NOT
// re-load them -- that was round 1's 34 GB L2 stream). Partials exchanged via
// double-buffered LDS with ONE barrier per step; every wave redundantly
// computes h,c per-lane so the next step's v_readlane broadcasts are
// wave-local. x row is s_loaded one step ahead (unroll-by-2 double buffer).
__global__ __launch_bounds__(NT, 2)
void lstm_fused(const float* __restrict__ x,
                const float* __restrict__ wk,
                const float* __restrict__ rk,
                const float* __restrict__ bias,
                const float* __restrict__ dw,
                const float* __restrict__ db,
                float* __restrict__ out) {
    const int b    = blockIdx.x;
    const int tid  = threadIdx.x;
    const int lane = tid & 63;
    const int g    = tid & 255;                       // gate column
    const int kofs = __builtin_amdgcn_readfirstlane((tid >> 8) * KH); // 0 or 32, wave-uniform

    // ---- weights: pinned register-resident columns ----
    float wx[KH], wh[KH];
#pragma unroll
    for (int k = 0; k < KH; ++k) wx[k] = wk[(kofs + k) * NG + g];
#pragma unroll
    for (int k = 0; k < KH; ++k) wh[k] = rk[(kofs + k) * NG + g];
#pragma unroll
    for (int k = 0; k < KH; ++k) {
        asm volatile("" : "+v"(wx[k]));   // opaque: cannot be rematerialized by reload
        asm volatile("" : "+v"(wh[k]));
    }
    const float bg  = (kofs == 0) ? bias[g] : 0.0f;   // bias added once (half 0)
    const float dwl = dw[lane];
    const float db0 = db[0];

    __shared__ float zbuf[2][NT];

    float h = 0.0f, c = 0.0f;
    const float* __restrict__ xb   = x + (size_t)b * SS * FF;
    float* __restrict__       outb = out + (size_t)b * SS;

    float xsA[KH], xsB[KH];

    // preload x row for t=0
    {
        const int off = __builtin_amdgcn_readfirstlane(kofs);
#pragma unroll
        for (int k = 0; k < KH; ++k) xsA[k] = xb[off + k];
    }

    auto step = [&](int t, const float* __restrict__ xs) {
        const int bsel = t & 1;
        float a0 = bg, a1 = 0.0f, a2 = 0.0f, a3 = 0.0f;

        // h-contribution: v_readlane broadcast (h[l] lives in lane l of every wave)
        const int hb = __float_as_int(h);
#pragma unroll
        for (int k = 0; k < KH; k += 4) {
            a0 += __int_as_float(__builtin_amdgcn_readlane(hb, kofs + k + 0)) * wh[k + 0];
            a1 += __int_as_float(__builtin_amdgcn_readlane(hb, kofs + k + 1)) * wh[k + 1];
            a2 += __int_as_float(__builtin_amdgcn_readlane(hb, kofs + k + 2)) * wh[k + 2];
            a3 += __int_as_float(__builtin_amdgcn_readlane(hb, kofs + k + 3)) * wh[k + 3];
        }
        // x-contribution (SGPR-resident row, scalar-operand FMAs)
#pragma unroll
        for (int k = 0; k < KH; k += 4) {
            a0 += xs[k + 0] * wx[k + 0];
            a1 += xs[k + 1] * wx[k + 1];
            a2 += xs[k + 2] * wx[k + 2];
            a3 += xs[k + 3] * wx[k + 3];
        }
        zbuf[bsel][tid] = (a0 + a1) + (a2 + a3);
        __syncthreads();

        // combine halves; gate layout i,f,c,o
        const float zi = zbuf[bsel][lane]       + zbuf[bsel][256 + lane];
        const float zf = zbuf[bsel][64 + lane]  + zbuf[bsel][320 + lane];
        const float zc = zbuf[bsel][128 + lane] + zbuf[bsel][384 + lane];
        const float zo = zbuf[bsel][192 + lane] + zbuf[bsel][448 + lane];

        const float ig = sigmoidf_(zi);
        const float fg = sigmoidf_(zf);
        const float og = sigmoidf_(zo);
        c = fg * c + ig * tanhf_(zc);
        h = og * tanhf_(c);

        // fused dense + sigmoid: wave 0 reduces h . dense_w
        if ((tid >> 6) == 0) {
            float r = h * dwl;
#pragma unroll
            for (int m = 32; m >= 1; m >>= 1) r += __shfl_xor(r, m, 64);
            if (lane == 0) outb[t] = sigmoidf_(r + db0);
        }
    };

    for (int t = 0; t < SS; t += 2) {
        // prefetch row t+1 while computing step t
        {
            const int off = __builtin_amdgcn_readfirstlane((t + 1) * FF + kofs);
#pragma unroll
            for (int k = 0; k < KH; ++k) xsB[k] = xb[off + k];
        }
        step(t, xsA);
        // prefetch row t+2 while computing step t+1 (clamped; last iter reads valid mem)
        {
            const int t2  = (t + 2 < SS) ? (t + 2) : (SS - 1);
            const int off = __builtin_amdgcn_readfirstlane(t2 * FF + kofs);
#pragma unroll
            for (int k = 0; k < KH; ++k) xsA[k] = xb[off + k];
        }
        step(t + 1, xsB);
    }
}

extern "C" void kernel_launch(void* const* d_in, const int* in_sizes, int n_in,
                              void* d_out, int out_size, void* d_ws, size_t ws_size,
                              hipStream_t stream) {
    const float* x    = (const float*)d_in[0];
    const float* wk   = (const float*)d_in[1];
    const float* rk   = (const float*)d_in[2];
    const float* bias = (const float*)d_in[3];
    const float* dw   = (const float*)d_in[4];
    const float* db   = (const float*)d_in[5];
    float* out = (float*)d_out;

    hipLaunchKernelGGL(lstm_fused, dim3(256), dim3(NT), 0, stream,
                       x, wk, rk, bias, dw, db, out);
}